// Round 18
// baseline (146.099 us; speedup 1.0000x reference)
//
#include <hip/hip_runtime.h>

typedef unsigned short u16;
typedef __bf16 bf16;
typedef float f32x4 __attribute__((ext_vector_type(4)));
typedef bf16 bf16x8 __attribute__((ext_vector_type(8)));
typedef u16 u16x4 __attribute__((ext_vector_type(4)));
typedef u16 u16x8 __attribute__((ext_vector_type(8)));

#define SEQ 2048
#define LOG2E 1.4426950408889634f

__device__ __forceinline__ u16 f2bf(float f) {
    return __builtin_bit_cast(u16, (bf16)f);
}
__device__ __forceinline__ float bf2f(u16 u) {
    unsigned int w = ((unsigned int)u) << 16;
    return __builtin_bit_cast(float, w);
}

// ---------------- fused prep: x cast (blocks 0..2047) + all 4 weight transposes ----------------
__global__ __launch_bounds__(256) void prep_k(const float* __restrict__ x,
                                              const float* __restrict__ wq,
                                              const float* __restrict__ wk,
                                              const float* __restrict__ wv,
                                              const float* __restrict__ wo,
                                              u16* __restrict__ xb,
                                              u16* __restrict__ wqkvt,
                                              u16* __restrict__ wot) {
    __shared__ float t[64][65];
    int b = blockIdx.x;
    if (b < 2048) {
        int i = b * 256 + threadIdx.x;
#pragma unroll
        for (int it = 0; it < 2; ++it, i += 524288) {
            float4 v = reinterpret_cast<const float4*>(x)[i];
            u16x4 o;
            o[0] = f2bf(v.x); o[1] = f2bf(v.y); o[2] = f2bf(v.z); o[3] = f2bf(v.w);
            reinterpret_cast<u16x4*>(xb)[i] = o;
        }
        return;
    }
    b -= 2048;
    const float* src;
    u16* dst;
    int C, bx, by;
    if (b < 1024)      { src = wq; dst = wqkvt;                          C = 2048; bx = b & 31; by = b >> 5; }
    else if (b < 1280) { b -= 1024; src = wk; dst = wqkvt + (size_t)2048 * 2048; C = 512; bx = b & 7; by = b >> 3; }
    else if (b < 1536) { b -= 1280; src = wv; dst = wqkvt + (size_t)2560 * 2048; C = 512; bx = b & 7; by = b >> 3; }
    else               { b -= 1536; src = wo; dst = wot;                 C = 2048; bx = b & 31; by = b >> 5; }
    int c0 = bx * 64, r0 = by * 64;
    int tx = threadIdx.x & 63, ty = threadIdx.x >> 6;
#pragma unroll
    for (int i = 0; i < 16; ++i) {
        int r = ty + i * 4;
        t[r][tx] = src[(size_t)(r0 + r) * C + c0 + tx];
    }
    __syncthreads();
#pragma unroll
    for (int i = 0; i < 16; ++i) {
        int c = ty + i * 4;
        dst[(size_t)(c0 + c) * 2048 + r0 + tx] = f2bf(t[tx][c]);
    }
}

// ---------------- GEMM: C[M,N] = A[M,K] @ Bt[N,K]^T, no split-K ----------------
// 128x128 tile, BK=32, 8 thin waves (512 thr, 2x4 acc each), dbuf + XOR LDS swizzle
// + bijective XCD swizzle. TOUT = u16 (bf16 C) or float (f32 C, direct to d_out).
// R17 post-mortem: per-block-iteration cost (~1000 cyc) is invariant to occupancy
// (24%->46%: null), vmcnt depth (R14: null), block count (R13: negative) -> this is
// the 2-phase structure ceiling (matches guide m233/m248: 607-655 TF; we: 651).
// Split-K therefore bought nothing; dropped to delete partial-sum traffic/kernels.
template <typename TOUT>
__global__ __launch_bounds__(512) void gemm_bt_k(const u16* __restrict__ A,
                                                 const u16* __restrict__ Bt,
                                                 TOUT* __restrict__ Cp,
                                                 int M, int N, int K) {
    __shared__ __align__(16) u16 As[2][128 * 32];
    __shared__ __align__(16) u16 Bs[2][128 * 32];
    int tid = threadIdx.x;
    int wave = tid >> 6, lane = tid & 63;

    // XCD-aware bijective work remap (nwg % 8 == 0 for both grids: 384, 256)
    unsigned nx = gridDim.x, ny = gridDim.y;
    unsigned nwg = nx * ny;
    unsigned id = blockIdx.x + nx * blockIdx.y;
    unsigned qq = nwg >> 3;
    unsigned swz = (id & 7) * qq + (id >> 3);
    unsigned bxw = swz % nx;
    unsigned byw = swz / nx;
    int bm = byw * 128, bn = bxw * 128;

    int wm = (wave >> 1) * 32, wn = (wave & 1) * 64;
    int g = lane >> 4, cidx = lane & 15;
    f32x4 acc[2][4] = {};

    int srow = lane >> 2;
    int skol = ((lane & 3) ^ ((srow >> 1) & 3)) * 8;
    int sl8 = (g ^ ((cidx >> 1) & 3)) * 8;

#define STAGE(buf, kt)                                                                \
    {                                                                                 \
        const u16* gpa = A + (size_t)(bm + wave * 16 + srow) * K + (kt) + skol;       \
        __builtin_amdgcn_global_load_lds(                                             \
            (__attribute__((address_space(1))) void*)gpa,                             \
            (__attribute__((address_space(3))) void*)&As[buf][wave * 512],            \
            16, 0, 0);                                                                \
        const u16* gpb = Bt + (size_t)(bn + wave * 16 + srow) * K + (kt) + skol;      \
        __builtin_amdgcn_global_load_lds(                                             \
            (__attribute__((address_space(1))) void*)gpb,                             \
            (__attribute__((address_space(3))) void*)&Bs[buf][wave * 512],            \
            16, 0, 0);                                                                \
    }

    STAGE(0, 0);
    asm volatile("s_waitcnt vmcnt(0)" ::: "memory");
    __syncthreads();

    int cur = 0;
#pragma unroll 1
    for (int kt = 0; kt < K; kt += 32) {
        if (kt + 32 < K) STAGE(cur ^ 1, kt + 32);

        bf16x8 af[2], bfr[4];
#pragma unroll
        for (int mi = 0; mi < 2; ++mi)
            af[mi] = *reinterpret_cast<const bf16x8*>(&As[cur][(wm + mi * 16 + cidx) * 32 + sl8]);
#pragma unroll
        for (int ni = 0; ni < 4; ++ni)
            bfr[ni] = *reinterpret_cast<const bf16x8*>(&Bs[cur][(wn + ni * 16 + cidx) * 32 + sl8]);
#pragma unroll
        for (int mi = 0; mi < 2; ++mi)
#pragma unroll
            for (int ni = 0; ni < 4; ++ni)
                acc[mi][ni] = __builtin_amdgcn_mfma_f32_16x16x32_bf16(af[mi], bfr[ni], acc[mi][ni], 0, 0, 0);

        asm volatile("s_waitcnt vmcnt(0)" ::: "memory");
        __syncthreads();
        cur ^= 1;
    }
#undef STAGE

#pragma unroll
    for (int mi = 0; mi < 2; ++mi) {
#pragma unroll
        for (int r = 0; r < 4; ++r) {
            int row = bm + wm + mi * 16 + g * 4 + r;
            TOUT* cp = Cp + (size_t)row * N + bn + wn + cidx;
#pragma unroll
            for (int ni = 0; ni < 4; ++ni) {
                float v = acc[mi][ni][r];
                if constexpr (__is_same(TOUT, u16)) cp[ni * 16] = f2bf(v);
                else                                cp[ni * 16] = v;
            }
        }
    }
}

// ---------------- fused post-GEMM1: RMSNorm+RoPE (blocks 0..20479) + V-frag ----------------
// Reads GEMM1's single bf16 qkv [2048][3072] (no split-K partials anymore).
__global__ __launch_bounds__(256) void postgemm_k(const u16* __restrict__ qkv,
                                                  const float* __restrict__ cosb,
                                                  const float* __restrict__ sinb,
                                                  const float* __restrict__ qw,
                                                  const float* __restrict__ kw,
                                                  u16* __restrict__ qn,
                                                  u16* __restrict__ kfrag,
                                                  u16* __restrict__ vfrag) {
    __shared__ float t[64][65];
    int b = blockIdx.x;
    if (b < 20480) {
        int idx = b * 4 + (threadIdx.x >> 6);
        int lane = threadIdx.x & 63;
        int s = idx / 40, hh = idx - s * 40;
        size_t off = (hh < 32) ? ((size_t)s * 3072 + hh * 64 + lane)
                               : ((size_t)s * 3072 + 2048 + (hh - 32) * 64 + lane);
        float val = bf2f(qkv[off]);
        float ss = val * val;
#pragma unroll
        for (int mm = 32; mm; mm >>= 1) ss += __shfl_xor(ss, mm);
        float w = (hh < 32) ? qw[lane] : kw[lane];
        float xn = val * rsqrtf(ss * (1.f / 64.f) + 1e-6f) * w;
        float part = __shfl_xor(xn, 32);
        float rot = (lane < 32) ? -part : part;
        float o = xn * cosb[s * 64 + lane] + rot * sinb[s * 64 + lane];
        if (hh < 32) {
            qn[(size_t)s * 2048 + hh * 64 + lane] = f2bf(o * (0.125f * LOG2E));
        } else {
            int h8 = hh - 32;
            int k32 = s & 31;
            int p32 = ((k32 >> 2) & 1) * 16 + ((k32 >> 3) << 2) + (k32 & 3);
            int p = (s & ~31) + p32;
            kfrag[(((size_t)h8 * 128 + (p >> 4)) << 10) + (lane >> 3) * 128 + (p & 15) * 8 + (lane & 7)] = f2bf(o);
        }
        return;
    }
    int vb = b - 20480;
    int s0 = (vb & 31) * 64, h = vb >> 5;
    int tx = threadIdx.x & 63, ty = threadIdx.x >> 6;
#pragma unroll
    for (int i = 0; i < 16; ++i) {
        int r = ty + i * 4;
        t[r][tx] = bf2f(qkv[(size_t)(s0 + r) * 3072 + 2560 + h * 64 + tx]);
    }
    __syncthreads();
    int dt = threadIdx.x >> 6, g = (threadIdx.x >> 4) & 3, cc = threadIdx.x & 15;
#pragma unroll
    for (int kb = 0; kb < 2; ++kb) {
        u16x8 o;
#pragma unroll
        for (int i = 0; i < 8; ++i) o[i] = f2bf(t[kb * 32 + g * 8 + i][dt * 16 + cc]);
        *reinterpret_cast<u16x8*>(
            &vfrag[((size_t)h * 64 + (s0 >> 5) + kb) * 2048 + dt * 512 + (size_t)(threadIdx.x & 63) * 8]) = o;
    }
}

// ---------------- Flash attention: 32 q-rows/wave, register-lifetime-ordered phases ----------------
// (R16 structure, unchanged)
__global__ __launch_bounds__(64, 4) void attn_k(const u16* __restrict__ qn,
                                                const u16* __restrict__ kfrag,
                                                const u16* __restrict__ vfrag,
                                                u16* __restrict__ obuf,
                                                float* __restrict__ lbuf) {
    int h = blockIdx.x;
    int kvh = h >> 2;
    int lane = threadIdx.x;
    int item = 159 - blockIdx.y;
    int t, w;
    if (item < 16)      { t = item;                    w = 0; }
    else if (item < 48) { t = 16 + ((item - 16) >> 1); w = (item - 16) & 1; }
    else if (item < 96) { int r = item - 48; int q = r / 3; t = 32 + q; w = r - 3 * q; }
    else                { t = 48 + ((item - 96) >> 2); w = (item - 96) & 3; }

    int qA0 = t * 32;
    int qB0 = qA0 + 16;
    int kv0 = w * 512;
    int nkA = qA0 + 16, nkB = qB0 + 16;
    int kvend = (kv0 + 512 < nkB) ? (kv0 + 512) : nkB;

    int g = lane >> 4, cc = lane & 15;
    int qrowA = qA0 + cc, qrowB = qB0 + cc;

    const size_t qoffA = (size_t)qrowA * 2048 + h * 64;
    const size_t qoffB = (size_t)qrowB * 2048 + h * 64;
    bf16x8 qa0 = *reinterpret_cast<const bf16x8*>(&qn[qoffA + g * 8]);
    bf16x8 qa1 = *reinterpret_cast<const bf16x8*>(&qn[qoffA + 32 + g * 8]);
    bf16x8 qb0 = *reinterpret_cast<const bf16x8*>(&qn[qoffB + g * 8]);
    bf16x8 qb1 = *reinterpret_cast<const bf16x8*>(&qn[qoffB + 32 + g * 8]);

    float lA = 0.f, lB = 0.f;
    f32x4 oA[4] = {}, oB[4] = {};

    const u16* kbase = kfrag + (((size_t)kvh * 128) << 10) + lane * 8;
    const u16* vbase = vfrag + (size_t)kvh * 64 * 2048 + lane * 8;

#pragma unroll 1
    for (; kv0 < kvend; kv0 += 64) {
        bool doA = kv0 < nkA;
        u16x8 pbA[2], pbB[2];

        {
            bf16x8 kf0[4], kf1[4];
#pragma unroll
            for (int sub = 0; sub < 4; ++sub) {
                const u16* kp = kbase + (size_t)((kv0 >> 4) + sub) * 1024;
                kf0[sub] = *reinterpret_cast<const bf16x8*>(kp);
                kf1[sub] = *reinterpret_cast<const bf16x8*>(kp + 512);
            }
            if (doA) {
                f32x4 st[4];
                __builtin_amdgcn_s_setprio(1);
#pragma unroll
                for (int sub = 0; sub < 4; ++sub) {
                    st[sub] = __builtin_amdgcn_mfma_f32_16x16x32_bf16(kf0[sub], qa0, (f32x4){0.f, 0.f, 0.f, 0.f}, 0, 0, 0);
                    st[sub] = __builtin_amdgcn_mfma_f32_16x16x32_bf16(kf1[sub], qa1, st[sub], 0, 0, 0);
                }
                __builtin_amdgcn_s_setprio(0);
                if (kv0 + 64 > qA0) {
#pragma unroll
                    for (int sub = 0; sub < 4; ++sub)
#pragma unroll
                        for (int r = 0; r < 4; ++r) {
                            int key = kv0 + (sub >> 1) * 32 + g * 8 + (sub & 1) * 4 + r;
                            if (key > qrowA) st[sub][r] = -1e30f;
                        }
                }
                float rs = 0.f;
#pragma unroll
                for (int sub = 0; sub < 4; ++sub)
#pragma unroll
                    for (int r = 0; r < 4; ++r) {
                        float e = __builtin_amdgcn_exp2f(st[sub][r]);
                        rs += e;
                        pbA[sub >> 1][(sub & 1) * 4 + r] = f2bf(e);
                    }
                lA += rs;
            }
            f32x4 st[4];
            __builtin_amdgcn_s_setprio(1);
#pragma unroll
            for (int sub = 0; sub < 4; ++sub) {
                st[sub] = __builtin_amdgcn_mfma_f32_16x16x32_bf16(kf0[sub], qb0, (f32x4){0.f, 0.f, 0.f, 0.f}, 0, 0, 0);
                st[sub] = __builtin_amdgcn_mfma_f32_16x16x32_bf16(kf1[sub], qb1, st[sub], 0, 0, 0);
            }
            __builtin_amdgcn_s_setprio(0);
            if (kv0 + 64 > qB0) {
#pragma unroll
                for (int sub = 0; sub < 4; ++sub)
#pragma unroll
                    for (int r = 0; r < 4; ++r) {
                        int key = kv0 + (sub >> 1) * 32 + g * 8 + (sub & 1) * 4 + r;
                        if (key > qrowB) st[sub][r] = -1e30f;
                    }
            }
            float rs = 0.f;
#pragma unroll
            for (int sub = 0; sub < 4; ++sub)
#pragma unroll
                for (int r = 0; r < 4; ++r) {
                    float e = __builtin_amdgcn_exp2f(st[sub][r]);
                    rs += e;
                    pbB[sub >> 1][(sub & 1) * 4 + r] = f2bf(e);
                }
            lB += rs;
        }

        bf16x8 vv[2][4];
#pragma unroll
        for (int sp = 0; sp < 2; ++sp)
#pragma unroll
            for (int dt = 0; dt < 4; ++dt)
                vv[sp][dt] = *reinterpret_cast<const bf16x8*>(
                    vbase + (size_t)((kv0 >> 5) + sp) * 2048 + dt * 512);

        __builtin_amdgcn_s_setprio(1);
#pragma unroll
        for (int sp = 0; sp < 2; ++sp) {
            bf16x8 pa = __builtin_bit_cast(bf16x8, pbA[sp]);
            bf16x8 pb = __builtin_bit_cast(bf16x8, pbB[sp]);
#pragma unroll
            for (int dt = 0; dt < 4; ++dt) {
                if (doA) oA[dt] = __builtin_amdgcn_mfma_f32_16x16x32_bf16(vv[sp][dt], pa, oA[dt], 0, 0, 0);
                oB[dt] = __builtin_amdgcn_mfma_f32_16x16x32_bf16(vv[sp][dt], pb, oB[dt], 0, 0, 0);
            }
        }
        __builtin_amdgcn_s_setprio(0);
    }

    lA += __shfl_xor(lA, 16);
    lA += __shfl_xor(lA, 32);
    lB += __shfl_xor(lB, 16);
    lB += __shfl_xor(lB, 32);
    size_t slotA = ((size_t)h * 160 + item) * 2;
    if (lane < 16) {
        lbuf[slotA * 16 + cc] = lA;
        lbuf[(slotA + 1) * 16 + cc] = lB;
    }
    u16* spA = obuf + slotA * 1024;
    u16* spB = obuf + (slotA + 1) * 1024;
#pragma unroll
    for (int dt = 0; dt < 4; ++dt) {
        u16x4 ovA, ovB;
#pragma unroll
        for (int r = 0; r < 4; ++r) {
            ovA[r] = f2bf(oA[dt][r]);
            ovB[r] = f2bf(oB[dt][r]);
        }
        *reinterpret_cast<u16x4*>(&spA[cc * 64 + dt * 16 + g * 4]) = ovA;
        *reinterpret_cast<u16x4*>(&spB[cc * 64 + dt * 16 + g * 4]) = ovB;
    }
}

// ---------------- merge: attn_bf16 = sum(o_w) / (sum(l_w) + 2^(sink*log2e)) ----------------
__global__ __launch_bounds__(256) void merge_k(const u16* __restrict__ obuf,
                                               const float* __restrict__ lbuf,
                                               const float* __restrict__ sink,
                                               u16* __restrict__ attnb) {
    int row = blockIdx.x;
    int c = row >> 4, cc = row & 15;
    int t2 = c >> 1, half = c & 1;
    int nw = (t2 >> 4) + 1;
    int jb = (t2 < 16) ? t2
           : (t2 < 32) ? 16 + ((t2 - 16) << 1)
           : (t2 < 48) ? 48 + 3 * (t2 - 32)
                       : 96 + ((t2 - 48) << 2);
    int t = threadIdx.x;
    int h = t >> 3, col0 = (t & 7) * 8;

    float acc[8] = {};
    float lsum = __builtin_amdgcn_exp2f(sink[h] * LOG2E);
#pragma unroll 1
    for (int w = 0; w < nw; ++w) {
        size_t slot = ((size_t)h * 160 + jb + w) * 2 + half;
        lsum += lbuf[slot * 16 + cc];
        u16x8 v = *reinterpret_cast<const u16x8*>(&obuf[slot * 1024 + cc * 64 + col0]);
#pragma unroll
        for (int i = 0; i < 8; ++i) acc[i] += bf2f(v[i]);
    }
    float inv = 1.f / lsum;
    u16x8 ob;
#pragma unroll
    for (int i = 0; i < 8; ++i) ob[i] = f2bf(acc[i] * inv);
    *reinterpret_cast<u16x8*>(&attnb[(size_t)row * 2048 + h * 64 + col0]) = ob;
}

extern "C" void kernel_launch(void* const* d_in, const int* in_sizes, int n_in,
                              void* d_out, int out_size, void* d_ws, size_t ws_size,
                              hipStream_t stream) {
    const float* x    = (const float*)d_in[0];
    const float* cosb = (const float*)d_in[2];
    const float* sinb = (const float*)d_in[3];
    const float* wq   = (const float*)d_in[4];
    const float* wk   = (const float*)d_in[5];
    const float* wv   = (const float*)d_in[6];
    const float* wo   = (const float*)d_in[7];
    const float* qw   = (const float*)d_in[8];
    const float* kw   = (const float*)d_in[9];
    const float* sink = (const float*)d_in[10];
    float* out = (float*)d_out;

    char* ws = (char*)d_ws;
    size_t off = 0;
    auto alloc = [&](size_t bytes) {
        char* p = ws + off;
        off += (bytes + 255) & ~(size_t)255;
        return p;
    };
    u16*   xb    = (u16*)alloc((size_t)2048 * 2048 * 2);   // x bf16
    u16*   wqkvt = (u16*)alloc((size_t)3072 * 2048 * 2);   // [wq^T; wk^T; wv^T]
    u16*   wot   = (u16*)alloc((size_t)2048 * 2048 * 2);   // wo^T
    u16*   qkv   = (u16*)alloc((size_t)2048 * 3072 * 2);   // GEMM1 output (bf16, no split-K)
    u16*   qnb   = (u16*)alloc((size_t)2048 * 2048 * 2);
    u16*   kfrag = (u16*)alloc((size_t)8 * 128 * 1024 * 2);
    u16*   vfrag = (u16*)alloc((size_t)8 * 64 * 2048 * 2);
    float* lbuf  = (float*)alloc((size_t)32 * 320 * 16 * 4);
    u16*   obuf  = (u16*)alloc((size_t)32 * 320 * 2 * 1024 * 2);  // 21 MB partial slots
    u16*   attnb = xb;   // xb dead after GEMM1

    prep_k<<<4608, 256, 0, stream>>>(x, wq, wk, wv, wo, xb, wqkvt, wot);

    gemm_bt_k<u16><<<dim3(24, 16), 512, 0, stream>>>(xb, wqkvt, qkv, 2048, 3072, 2048);
    postgemm_k<<<20736, 256, 0, stream>>>(qkv, cosb, sinb, qw, kw, qnb, kfrag, vfrag);

    attn_k<<<dim3(32, 160), 64, 0, stream>>>(qnb, kfrag, vfrag, obuf, lbuf);
    merge_k<<<2048, 256, 0, stream>>>(obuf, lbuf, sink, attnb);

    gemm_bt_k<float><<<dim3(16, 16), 512, 0, stream>>>(attnb, wot, out, 2048, 2048, 2048);
}

// Round 19
// 145.609 us; speedup vs baseline: 1.0034x; 1.0034x over previous
//
#include <hip/hip_runtime.h>

typedef unsigned short u16;
typedef __bf16 bf16;
typedef float f32x4 __attribute__((ext_vector_type(4)));
typedef bf16 bf16x8 __attribute__((ext_vector_type(8)));
typedef u16 u16x4 __attribute__((ext_vector_type(4)));
typedef u16 u16x8 __attribute__((ext_vector_type(8)));

#define SEQ 2048
#define LOG2E 1.4426950408889634f

__device__ __forceinline__ u16 f2bf(float f) {
    return __builtin_bit_cast(u16, (bf16)f);
}
__device__ __forceinline__ float bf2f(u16 u) {
    unsigned int w = ((unsigned int)u) << 16;
    return __builtin_bit_cast(float, w);
}

// ---------------- fused prep: x cast (blocks 0..2047) + all 4 weight transposes ----------------
__global__ __launch_bounds__(256) void prep_k(const float* __restrict__ x,
                                              const float* __restrict__ wq,
                                              const float* __restrict__ wk,
                                              const float* __restrict__ wv,
                                              const float* __restrict__ wo,
                                              u16* __restrict__ xb,
                                              u16* __restrict__ wqkvt,
                                              u16* __restrict__ wot) {
    __shared__ float t[64][65];
    int b = blockIdx.x;
    if (b < 2048) {
        int i = b * 256 + threadIdx.x;
#pragma unroll
        for (int it = 0; it < 2; ++it, i += 524288) {
            float4 v = reinterpret_cast<const float4*>(x)[i];
            u16x4 o;
            o[0] = f2bf(v.x); o[1] = f2bf(v.y); o[2] = f2bf(v.z); o[3] = f2bf(v.w);
            reinterpret_cast<u16x4*>(xb)[i] = o;
        }
        return;
    }
    b -= 2048;
    const float* src;
    u16* dst;
    int C, bx, by;
    if (b < 1024)      { src = wq; dst = wqkvt;                          C = 2048; bx = b & 31; by = b >> 5; }
    else if (b < 1280) { b -= 1024; src = wk; dst = wqkvt + (size_t)2048 * 2048; C = 512; bx = b & 7; by = b >> 3; }
    else if (b < 1536) { b -= 1280; src = wv; dst = wqkvt + (size_t)2560 * 2048; C = 512; bx = b & 7; by = b >> 3; }
    else               { b -= 1536; src = wo; dst = wot;                 C = 2048; bx = b & 31; by = b >> 5; }
    int c0 = bx * 64, r0 = by * 64;
    int tx = threadIdx.x & 63, ty = threadIdx.x >> 6;
#pragma unroll
    for (int i = 0; i < 16; ++i) {
        int r = ty + i * 4;
        t[r][tx] = src[(size_t)(r0 + r) * C + c0 + tx];
    }
    __syncthreads();
#pragma unroll
    for (int i = 0; i < 16; ++i) {
        int c = ty + i * 4;
        dst[(size_t)(c0 + c) * 2048 + r0 + tx] = f2bf(t[tx][c]);
    }
}

// ---------------- GEMM partial: Cp[z][M,N](bf16) = A[M,kz] @ Bt[N,kz]^T ----------------
// R19: 256x128 tile (BM=256), BK=32, split-K=2 (restored: R18 showed z=1 doubles
// per-XCD footprint -> FETCH 29->53MB, +6us/GEMM). 8 waves x 64x64 sub-tile
// (acc 4x4 = 64 AGPR, ~115 unified regs under the (512,4) 128 cap -> 2 blocks/CU
// at 48KB LDS). HALVES total block-iterations — the one quantity GEMM time tracked
// across R12-R18 (~990 cyc/block-iter, invariant to occupancy/vmcnt/block count).
// dbuf + XOR LDS swizzle + bijective XCD swizzle retained.
__global__ __launch_bounds__(512, 4) void gemm_bt_k(const u16* __restrict__ A,
                                                    const u16* __restrict__ Bt,
                                                    u16* __restrict__ Cp,
                                                    int M, int N, int K) {
    __shared__ __align__(16) u16 As[2][256 * 32];
    __shared__ __align__(16) u16 Bs[2][128 * 32];
    int tid = threadIdx.x;
    int wave = tid >> 6, lane = tid & 63;

    // XCD-aware bijective work remap (nwg % 8 == 0: 384, 256)
    unsigned nx = gridDim.x, ny = gridDim.y;
    unsigned nwg = nx * ny * gridDim.z;
    unsigned id = blockIdx.x + nx * (blockIdx.y + ny * blockIdx.z);
    unsigned qq = nwg >> 3;
    unsigned swz = (id & 7) * qq + (id >> 3);
    unsigned bxw = swz % nx;
    unsigned rem = swz / nx;
    unsigned byw = rem % ny;
    unsigned bzw = rem / ny;
    int bm = byw * 256, bn = bxw * 128;
    int z = bzw;

    int kslice = K / gridDim.z;
    int kt0 = z * kslice, ktend = kt0 + kslice;
    int wm = (wave >> 1) * 64, wn = (wave & 1) * 64;
    int g = lane >> 4, cidx = lane & 15;
    f32x4 acc[4][4] = {};

    int srow = lane >> 2;
    int skol = ((lane & 3) ^ ((srow >> 1) & 3)) * 8;
    int sl8 = (g ^ ((cidx >> 1) & 3)) * 8;

    // 24 staging chunks of 16 rows (A: 0..15, B: 16..23); wave stages chunks 3w..3w+2
#define STAGE(buf, kt)                                                                 \
    {                                                                                  \
        _Pragma("unroll")                                                              \
        for (int j = 0; j < 3; ++j) {                                                  \
            int c = wave * 3 + j;                                                      \
            if (c < 16) {                                                              \
                const u16* gp = A + (size_t)(bm + c * 16 + srow) * K + (kt) + skol;    \
                __builtin_amdgcn_global_load_lds(                                      \
                    (__attribute__((address_space(1))) void*)gp,                       \
                    (__attribute__((address_space(3))) void*)&As[buf][c * 512],        \
                    16, 0, 0);                                                         \
            } else {                                                                   \
                const u16* gp = Bt + (size_t)(bn + (c - 16) * 16 + srow) * K + (kt) + skol; \
                __builtin_amdgcn_global_load_lds(                                      \
                    (__attribute__((address_space(1))) void*)gp,                       \
                    (__attribute__((address_space(3))) void*)&Bs[buf][(c - 16) * 512], \
                    16, 0, 0);                                                         \
            }                                                                          \
        }                                                                              \
    }

    STAGE(0, kt0);
    asm volatile("s_waitcnt vmcnt(0)" ::: "memory");
    __syncthreads();

    int cur = 0;
#pragma unroll 1
    for (int kt = kt0; kt < ktend; kt += 32) {
        if (kt + 32 < ktend) STAGE(cur ^ 1, kt + 32);

        bf16x8 bfr[4];
#pragma unroll
        for (int ni = 0; ni < 4; ++ni)
            bfr[ni] = *reinterpret_cast<const bf16x8*>(&Bs[cur][(wn + ni * 16 + cidx) * 32 + sl8]);
#pragma unroll
        for (int mi = 0; mi < 4; ++mi) {
            bf16x8 af = *reinterpret_cast<const bf16x8*>(&As[cur][(wm + mi * 16 + cidx) * 32 + sl8]);
#pragma unroll
            for (int ni = 0; ni < 4; ++ni)
                acc[mi][ni] = __builtin_amdgcn_mfma_f32_16x16x32_bf16(af, bfr[ni], acc[mi][ni], 0, 0, 0);
        }

        asm volatile("s_waitcnt vmcnt(0)" ::: "memory");
        __syncthreads();
        cur ^= 1;
    }
#undef STAGE

    u16* cbase = Cp + (size_t)z * M * N;
#pragma unroll
    for (int mi = 0; mi < 4; ++mi) {
#pragma unroll
        for (int r = 0; r < 4; ++r) {
            int row = bm + wm + mi * 16 + g * 4 + r;
            u16* cp = cbase + (size_t)row * N + bn + wn + cidx;
#pragma unroll
            for (int ni = 0; ni < 4; ++ni)
                cp[ni * 16] = f2bf(acc[mi][ni][r]);
        }
    }
}

// ---------------- sum two bf16 partials -> f32 ----------------
__global__ __launch_bounds__(256) void sum2_f32_k(const u16* __restrict__ a,
                                                  const u16* __restrict__ b,
                                                  float* __restrict__ out, int n8) {
    int i = blockIdx.x * 256 + threadIdx.x;
    if (i >= n8) return;
    u16x8 va = reinterpret_cast<const u16x8*>(a)[i];
    u16x8 vb = reinterpret_cast<const u16x8*>(b)[i];
    f32x4 lo, hi;
#pragma unroll
    for (int j = 0; j < 4; ++j) {
        lo[j] = bf2f(va[j]) + bf2f(vb[j]);
        hi[j] = bf2f(va[4 + j]) + bf2f(vb[4 + j]);
    }
    reinterpret_cast<f32x4*>(out)[i * 2] = lo;
    reinterpret_cast<f32x4*>(out)[i * 2 + 1] = hi;
}

// ---------------- fused post-GEMM1: RMSNorm+RoPE (blocks 0..20479) + V-frag ----------------
__global__ __launch_bounds__(256) void postgemm_k(const u16* __restrict__ p0,
                                                  const u16* __restrict__ p1,
                                                  const float* __restrict__ cosb,
                                                  const float* __restrict__ sinb,
                                                  const float* __restrict__ qw,
                                                  const float* __restrict__ kw,
                                                  u16* __restrict__ qn,
                                                  u16* __restrict__ kfrag,
                                                  u16* __restrict__ vfrag) {
    __shared__ float t[64][65];
    int b = blockIdx.x;
    if (b < 20480) {
        int idx = b * 4 + (threadIdx.x >> 6);
        int lane = threadIdx.x & 63;
        int s = idx / 40, hh = idx - s * 40;
        size_t off = (hh < 32) ? ((size_t)s * 3072 + hh * 64 + lane)
                               : ((size_t)s * 3072 + 2048 + (hh - 32) * 64 + lane);
        float val = bf2f(p0[off]) + bf2f(p1[off]);
        float ss = val * val;
#pragma unroll
        for (int mm = 32; mm; mm >>= 1) ss += __shfl_xor(ss, mm);
        float w = (hh < 32) ? qw[lane] : kw[lane];
        float xn = val * rsqrtf(ss * (1.f / 64.f) + 1e-6f) * w;
        float part = __shfl_xor(xn, 32);
        float rot = (lane < 32) ? -part : part;
        float o = xn * cosb[s * 64 + lane] + rot * sinb[s * 64 + lane];
        if (hh < 32) {
            qn[(size_t)s * 2048 + hh * 64 + lane] = f2bf(o * (0.125f * LOG2E));
        } else {
            int h8 = hh - 32;
            int k32 = s & 31;
            int p32 = ((k32 >> 2) & 1) * 16 + ((k32 >> 3) << 2) + (k32 & 3);
            int p = (s & ~31) + p32;
            kfrag[(((size_t)h8 * 128 + (p >> 4)) << 10) + (lane >> 3) * 128 + (p & 15) * 8 + (lane & 7)] = f2bf(o);
        }
        return;
    }
    int vb = b - 20480;
    int s0 = (vb & 31) * 64, h = vb >> 5;
    int tx = threadIdx.x & 63, ty = threadIdx.x >> 6;
#pragma unroll
    for (int i = 0; i < 16; ++i) {
        int r = ty + i * 4;
        size_t off = (size_t)(s0 + r) * 3072 + 2560 + h * 64 + tx;
        t[r][tx] = bf2f(p0[off]) + bf2f(p1[off]);
    }
    __syncthreads();
    int dt = threadIdx.x >> 6, g = (threadIdx.x >> 4) & 3, cc = threadIdx.x & 15;
#pragma unroll
    for (int kb = 0; kb < 2; ++kb) {
        u16x8 o;
#pragma unroll
        for (int i = 0; i < 8; ++i) o[i] = f2bf(t[kb * 32 + g * 8 + i][dt * 16 + cc]);
        *reinterpret_cast<u16x8*>(
            &vfrag[((size_t)h * 64 + (s0 >> 5) + kb) * 2048 + dt * 512 + (size_t)(threadIdx.x & 63) * 8]) = o;
    }
}

// ---------------- Flash attention: 32 q-rows/wave, register-lifetime-ordered phases ----------------
// (R16 structure, unchanged)
__global__ __launch_bounds__(64, 4) void attn_k(const u16* __restrict__ qn,
                                                const u16* __restrict__ kfrag,
                                                const u16* __restrict__ vfrag,
                                                u16* __restrict__ obuf,
                                                float* __restrict__ lbuf) {
    int h = blockIdx.x;
    int kvh = h >> 2;
    int lane = threadIdx.x;
    int item = 159 - blockIdx.y;
    int t, w;
    if (item < 16)      { t = item;                    w = 0; }
    else if (item < 48) { t = 16 + ((item - 16) >> 1); w = (item - 16) & 1; }
    else if (item < 96) { int r = item - 48; int q = r / 3; t = 32 + q; w = r - 3 * q; }
    else                { t = 48 + ((item - 96) >> 2); w = (item - 96) & 3; }

    int qA0 = t * 32;
    int qB0 = qA0 + 16;
    int kv0 = w * 512;
    int nkA = qA0 + 16, nkB = qB0 + 16;
    int kvend = (kv0 + 512 < nkB) ? (kv0 + 512) : nkB;

    int g = lane >> 4, cc = lane & 15;
    int qrowA = qA0 + cc, qrowB = qB0 + cc;

    const size_t qoffA = (size_t)qrowA * 2048 + h * 64;
    const size_t qoffB = (size_t)qrowB * 2048 + h * 64;
    bf16x8 qa0 = *reinterpret_cast<const bf16x8*>(&qn[qoffA + g * 8]);
    bf16x8 qa1 = *reinterpret_cast<const bf16x8*>(&qn[qoffA + 32 + g * 8]);
    bf16x8 qb0 = *reinterpret_cast<const bf16x8*>(&qn[qoffB + g * 8]);
    bf16x8 qb1 = *reinterpret_cast<const bf16x8*>(&qn[qoffB + 32 + g * 8]);

    float lA = 0.f, lB = 0.f;
    f32x4 oA[4] = {}, oB[4] = {};

    const u16* kbase = kfrag + (((size_t)kvh * 128) << 10) + lane * 8;
    const u16* vbase = vfrag + (size_t)kvh * 64 * 2048 + lane * 8;

#pragma unroll 1
    for (; kv0 < kvend; kv0 += 64) {
        bool doA = kv0 < nkA;
        u16x8 pbA[2], pbB[2];

        {
            bf16x8 kf0[4], kf1[4];
#pragma unroll
            for (int sub = 0; sub < 4; ++sub) {
                const u16* kp = kbase + (size_t)((kv0 >> 4) + sub) * 1024;
                kf0[sub] = *reinterpret_cast<const bf16x8*>(kp);
                kf1[sub] = *reinterpret_cast<const bf16x8*>(kp + 512);
            }
            if (doA) {
                f32x4 st[4];
                __builtin_amdgcn_s_setprio(1);
#pragma unroll
                for (int sub = 0; sub < 4; ++sub) {
                    st[sub] = __builtin_amdgcn_mfma_f32_16x16x32_bf16(kf0[sub], qa0, (f32x4){0.f, 0.f, 0.f, 0.f}, 0, 0, 0);
                    st[sub] = __builtin_amdgcn_mfma_f32_16x16x32_bf16(kf1[sub], qa1, st[sub], 0, 0, 0);
                }
                __builtin_amdgcn_s_setprio(0);
                if (kv0 + 64 > qA0) {
#pragma unroll
                    for (int sub = 0; sub < 4; ++sub)
#pragma unroll
                        for (int r = 0; r < 4; ++r) {
                            int key = kv0 + (sub >> 1) * 32 + g * 8 + (sub & 1) * 4 + r;
                            if (key > qrowA) st[sub][r] = -1e30f;
                        }
                }
                float rs = 0.f;
#pragma unroll
                for (int sub = 0; sub < 4; ++sub)
#pragma unroll
                    for (int r = 0; r < 4; ++r) {
                        float e = __builtin_amdgcn_exp2f(st[sub][r]);
                        rs += e;
                        pbA[sub >> 1][(sub & 1) * 4 + r] = f2bf(e);
                    }
                lA += rs;
            }
            f32x4 st[4];
            __builtin_amdgcn_s_setprio(1);
#pragma unroll
            for (int sub = 0; sub < 4; ++sub) {
                st[sub] = __builtin_amdgcn_mfma_f32_16x16x32_bf16(kf0[sub], qb0, (f32x4){0.f, 0.f, 0.f, 0.f}, 0, 0, 0);
                st[sub] = __builtin_amdgcn_mfma_f32_16x16x32_bf16(kf1[sub], qb1, st[sub], 0, 0, 0);
            }
            __builtin_amdgcn_s_setprio(0);
            if (kv0 + 64 > qB0) {
#pragma unroll
                for (int sub = 0; sub < 4; ++sub)
#pragma unroll
                    for (int r = 0; r < 4; ++r) {
                        int key = kv0 + (sub >> 1) * 32 + g * 8 + (sub & 1) * 4 + r;
                        if (key > qrowB) st[sub][r] = -1e30f;
                    }
            }
            float rs = 0.f;
#pragma unroll
            for (int sub = 0; sub < 4; ++sub)
#pragma unroll
                for (int r = 0; r < 4; ++r) {
                    float e = __builtin_amdgcn_exp2f(st[sub][r]);
                    rs += e;
                    pbB[sub >> 1][(sub & 1) * 4 + r] = f2bf(e);
                }
            lB += rs;
        }

        bf16x8 vv[2][4];
#pragma unroll
        for (int sp = 0; sp < 2; ++sp)
#pragma unroll
            for (int dt = 0; dt < 4; ++dt)
                vv[sp][dt] = *reinterpret_cast<const bf16x8*>(
                    vbase + (size_t)((kv0 >> 5) + sp) * 2048 + dt * 512);

        __builtin_amdgcn_s_setprio(1);
#pragma unroll
        for (int sp = 0; sp < 2; ++sp) {
            bf16x8 pa = __builtin_bit_cast(bf16x8, pbA[sp]);
            bf16x8 pb = __builtin_bit_cast(bf16x8, pbB[sp]);
#pragma unroll
            for (int dt = 0; dt < 4; ++dt) {
                if (doA) oA[dt] = __builtin_amdgcn_mfma_f32_16x16x32_bf16(vv[sp][dt], pa, oA[dt], 0, 0, 0);
                oB[dt] = __builtin_amdgcn_mfma_f32_16x16x32_bf16(vv[sp][dt], pb, oB[dt], 0, 0, 0);
            }
        }
        __builtin_amdgcn_s_setprio(0);
    }

    lA += __shfl_xor(lA, 16);
    lA += __shfl_xor(lA, 32);
    lB += __shfl_xor(lB, 16);
    lB += __shfl_xor(lB, 32);
    size_t slotA = ((size_t)h * 160 + item) * 2;
    if (lane < 16) {
        lbuf[slotA * 16 + cc] = lA;
        lbuf[(slotA + 1) * 16 + cc] = lB;
    }
    u16* spA = obuf + slotA * 1024;
    u16* spB = obuf + (slotA + 1) * 1024;
#pragma unroll
    for (int dt = 0; dt < 4; ++dt) {
        u16x4 ovA, ovB;
#pragma unroll
        for (int r = 0; r < 4; ++r) {
            ovA[r] = f2bf(oA[dt][r]);
            ovB[r] = f2bf(oB[dt][r]);
        }
        *reinterpret_cast<u16x4*>(&spA[cc * 64 + dt * 16 + g * 4]) = ovA;
        *reinterpret_cast<u16x4*>(&spB[cc * 64 + dt * 16 + g * 4]) = ovB;
    }
}

// ---------------- merge: attn_bf16 = sum(o_w) / (sum(l_w) + 2^(sink*log2e)) ----------------
__global__ __launch_bounds__(256) void merge_k(const u16* __restrict__ obuf,
                                               const float* __restrict__ lbuf,
                                               const float* __restrict__ sink,
                                               u16* __restrict__ attnb) {
    int row = blockIdx.x;
    int c = row >> 4, cc = row & 15;
    int t2 = c >> 1, half = c & 1;
    int nw = (t2 >> 4) + 1;
    int jb = (t2 < 16) ? t2
           : (t2 < 32) ? 16 + ((t2 - 16) << 1)
           : (t2 < 48) ? 48 + 3 * (t2 - 32)
                       : 96 + ((t2 - 48) << 2);
    int t = threadIdx.x;
    int h = t >> 3, col0 = (t & 7) * 8;

    float acc[8] = {};
    float lsum = __builtin_amdgcn_exp2f(sink[h] * LOG2E);
#pragma unroll 1
    for (int w = 0; w < nw; ++w) {
        size_t slot = ((size_t)h * 160 + jb + w) * 2 + half;
        lsum += lbuf[slot * 16 + cc];
        u16x8 v = *reinterpret_cast<const u16x8*>(&obuf[slot * 1024 + cc * 64 + col0]);
#pragma unroll
        for (int i = 0; i < 8; ++i) acc[i] += bf2f(v[i]);
    }
    float inv = 1.f / lsum;
    u16x8 ob;
#pragma unroll
    for (int i = 0; i < 8; ++i) ob[i] = f2bf(acc[i] * inv);
    *reinterpret_cast<u16x8*>(&attnb[(size_t)row * 2048 + h * 64 + col0]) = ob;
}

extern "C" void kernel_launch(void* const* d_in, const int* in_sizes, int n_in,
                              void* d_out, int out_size, void* d_ws, size_t ws_size,
                              hipStream_t stream) {
    const float* x    = (const float*)d_in[0];
    const float* cosb = (const float*)d_in[2];
    const float* sinb = (const float*)d_in[3];
    const float* wq   = (const float*)d_in[4];
    const float* wk   = (const float*)d_in[5];
    const float* wv   = (const float*)d_in[6];
    const float* wo   = (const float*)d_in[7];
    const float* qw   = (const float*)d_in[8];
    const float* kw   = (const float*)d_in[9];
    const float* sink = (const float*)d_in[10];
    float* out = (float*)d_out;

    char* ws = (char*)d_ws;
    size_t off = 0;
    auto alloc = [&](size_t bytes) {
        char* p = ws + off;
        off += (bytes + 255) & ~(size_t)255;
        return p;
    };
    u16*   xb    = (u16*)alloc((size_t)2048 * 2048 * 2);       // x bf16
    u16*   wqkvt = (u16*)alloc((size_t)3072 * 2048 * 2);       // [wq^T; wk^T; wv^T]
    u16*   wot   = (u16*)alloc((size_t)2048 * 2048 * 2);       // wo^T
    u16*   p0    = (u16*)alloc((size_t)2048 * 3072 * 2);       // GEMM1 partial z=0 (bf16)
    u16*   p1    = (u16*)alloc((size_t)2048 * 3072 * 2);       // GEMM1 partial z=1 (bf16)
    u16*   qnb   = (u16*)alloc((size_t)2048 * 2048 * 2);
    u16*   kfrag = (u16*)alloc((size_t)8 * 128 * 1024 * 2);
    u16*   vfrag = (u16*)alloc((size_t)8 * 64 * 2048 * 2);
    float* lbuf  = (float*)alloc((size_t)32 * 320 * 16 * 4);
    u16*   attnb = xb;        // xb dead after GEMM1
    u16*   obuf  = p0;        // p0+p1 dead after postgemm; obuf needs 21 MB
    u16*   o2p   = p0;        // obuf dead after merge_k; GEMM2 bf16 partials need 16.8 MB

    prep_k<<<4608, 256, 0, stream>>>(x, wq, wk, wv, wo, xb, wqkvt, wot);

    gemm_bt_k<<<dim3(24, 8, 2), 512, 0, stream>>>(xb, wqkvt, p0, 2048, 3072, 2048);
    postgemm_k<<<20736, 256, 0, stream>>>(p0, p1, cosb, sinb, qw, kw, qnb, kfrag, vfrag);

    attn_k<<<dim3(32, 160), 64, 0, stream>>>(qnb, kfrag, vfrag, obuf, lbuf);
    merge_k<<<2048, 256, 0, stream>>>(obuf, lbuf, sink, attnb);

    gemm_bt_k<<<dim3(16, 8, 2), 512, 0, stream>>>(attnb, wot, o2p, 2048, 2048, 2048);
    sum2_f32_k<<<2048, 256, 0, stream>>>(o2p, o2p + (size_t)2048 * 2048, out, 2048 * 2048 / 8);
}

// Round 20
// 137.487 us; speedup vs baseline: 1.0626x; 1.0591x over previous
//
#include <hip/hip_runtime.h>

typedef unsigned short u16;
typedef __bf16 bf16;
typedef float f32x4 __attribute__((ext_vector_type(4)));
typedef bf16 bf16x8 __attribute__((ext_vector_type(8)));
typedef u16 u16x4 __attribute__((ext_vector_type(4)));
typedef u16 u16x8 __attribute__((ext_vector_type(8)));

#define SEQ 2048
#define LOG2E 1.4426950408889634f

__device__ __forceinline__ u16 f2bf(float f) {
    return __builtin_bit_cast(u16, (bf16)f);
}
__device__ __forceinline__ float bf2f(u16 u) {
    unsigned int w = ((unsigned int)u) << 16;
    return __builtin_bit_cast(float, w);
}

// ---------------- fused prep: x cast (blocks 0..2047) + all 4 weight transposes ----------------
__global__ __launch_bounds__(256) void prep_k(const float* __restrict__ x,
                                              const float* __restrict__ wq,
                                              const float* __restrict__ wk,
                                              const float* __restrict__ wv,
                                              const float* __restrict__ wo,
                                              u16* __restrict__ xb,
                                              u16* __restrict__ wqkvt,
                                              u16* __restrict__ wot) {
    __shared__ float t[64][65];
    int b = blockIdx.x;
    if (b < 2048) {
        int i = b * 256 + threadIdx.x;
#pragma unroll
        for (int it = 0; it < 2; ++it, i += 524288) {
            float4 v = reinterpret_cast<const float4*>(x)[i];
            u16x4 o;
            o[0] = f2bf(v.x); o[1] = f2bf(v.y); o[2] = f2bf(v.z); o[3] = f2bf(v.w);
            reinterpret_cast<u16x4*>(xb)[i] = o;
        }
        return;
    }
    b -= 2048;
    const float* src;
    u16* dst;
    int C, bx, by;
    if (b < 1024)      { src = wq; dst = wqkvt;                          C = 2048; bx = b & 31; by = b >> 5; }
    else if (b < 1280) { b -= 1024; src = wk; dst = wqkvt + (size_t)2048 * 2048; C = 512; bx = b & 7; by = b >> 3; }
    else if (b < 1536) { b -= 1280; src = wv; dst = wqkvt + (size_t)2560 * 2048; C = 512; bx = b & 7; by = b >> 3; }
    else               { b -= 1536; src = wo; dst = wot;                 C = 2048; bx = b & 31; by = b >> 5; }
    int c0 = bx * 64, r0 = by * 64;
    int tx = threadIdx.x & 63, ty = threadIdx.x >> 6;
#pragma unroll
    for (int i = 0; i < 16; ++i) {
        int r = ty + i * 4;
        t[r][tx] = src[(size_t)(r0 + r) * C + c0 + tx];
    }
    __syncthreads();
#pragma unroll
    for (int i = 0; i < 16; ++i) {
        int c = ty + i * 4;
        dst[(size_t)(c0 + c) * 2048 + r0 + tx] = f2bf(t[tx][c]);
    }
}

// ---------------- GEMM partial: Cp[z][M,N](bf16) = A[M,kz] @ Bt[N,kz]^T ----------------
// R17 configuration (best measured: 39.6us each, ~650 TF = the 2-phase structure
// ceiling per guide m233/m248). 128x128 tile, BK=32, split-K=2 (footprint halving
// per XCD — its real value per R18's falsification of the occupancy theory), 8 thin
// waves (512 thr, 2x4 acc), dbuf + XOR LDS swizzle + bijective XCD swizzle (T1).
// Characterized invariants: time is NOT improved by occupancy (R17 24->46%: null),
// vmcnt depth (R14: null), block count (R13: negative), tile area (R19: null).
// 8-phase escape needs 256-wide tiles -> 64-96 blocks at these shapes (grid-starved).
__global__ __launch_bounds__(512) void gemm_bt_dbuf_k(const u16* __restrict__ A,
                                                      const u16* __restrict__ Bt,
                                                      u16* __restrict__ Cp,
                                                      int M, int N, int K) {
    __shared__ __align__(16) u16 As[2][128 * 32];
    __shared__ __align__(16) u16 Bs[2][128 * 32];
    int tid = threadIdx.x;
    int wave = tid >> 6, lane = tid & 63;

    // XCD-aware bijective work remap
    unsigned nx = gridDim.x, ny = gridDim.y;
    unsigned nwg = nx * ny * gridDim.z;
    unsigned id = blockIdx.x + nx * (blockIdx.y + ny * blockIdx.z);
    unsigned qq = nwg >> 3;
    unsigned swz = (id & 7) * qq + (id >> 3);
    unsigned bxw = swz % nx;
    unsigned rem = swz / nx;
    unsigned byw = rem % ny;
    unsigned bzw = rem / ny;
    int bm = byw * 128, bn = bxw * 128;
    int z = bzw;

    int kslice = K / gridDim.z;
    int kt0 = z * kslice, ktend = kt0 + kslice;
    int wm = (wave >> 1) * 32, wn = (wave & 1) * 64;
    int g = lane >> 4, cidx = lane & 15;
    f32x4 acc[2][4] = {};

    int srow = lane >> 2;
    int skol = ((lane & 3) ^ ((srow >> 1) & 3)) * 8;
    int sl8 = (g ^ ((cidx >> 1) & 3)) * 8;

#define STAGE(buf, kt)                                                                \
    {                                                                                 \
        const u16* gpa = A + (size_t)(bm + wave * 16 + srow) * K + (kt) + skol;       \
        __builtin_amdgcn_global_load_lds(                                             \
            (__attribute__((address_space(1))) void*)gpa,                             \
            (__attribute__((address_space(3))) void*)&As[buf][wave * 512],            \
            16, 0, 0);                                                                \
        const u16* gpb = Bt + (size_t)(bn + wave * 16 + srow) * K + (kt) + skol;      \
        __builtin_amdgcn_global_load_lds(                                             \
            (__attribute__((address_space(1))) void*)gpb,                             \
            (__attribute__((address_space(3))) void*)&Bs[buf][wave * 512],            \
            16, 0, 0);                                                                \
    }

    STAGE(0, kt0);
    asm volatile("s_waitcnt vmcnt(0)" ::: "memory");
    __syncthreads();

    int cur = 0;
#pragma unroll 1
    for (int kt = kt0; kt < ktend; kt += 32) {
        if (kt + 32 < ktend) STAGE(cur ^ 1, kt + 32);

        bf16x8 af[2], bfr[4];
#pragma unroll
        for (int mi = 0; mi < 2; ++mi)
            af[mi] = *reinterpret_cast<const bf16x8*>(&As[cur][(wm + mi * 16 + cidx) * 32 + sl8]);
#pragma unroll
        for (int ni = 0; ni < 4; ++ni)
            bfr[ni] = *reinterpret_cast<const bf16x8*>(&Bs[cur][(wn + ni * 16 + cidx) * 32 + sl8]);
#pragma unroll
        for (int mi = 0; mi < 2; ++mi)
#pragma unroll
            for (int ni = 0; ni < 4; ++ni)
                acc[mi][ni] = __builtin_amdgcn_mfma_f32_16x16x32_bf16(af[mi], bfr[ni], acc[mi][ni], 0, 0, 0);

        asm volatile("s_waitcnt vmcnt(0)" ::: "memory");
        __syncthreads();
        cur ^= 1;
    }
#undef STAGE

    u16* cbase = Cp + (size_t)z * M * N;
#pragma unroll
    for (int mi = 0; mi < 2; ++mi) {
#pragma unroll
        for (int r = 0; r < 4; ++r) {
            int row = bm + wm + mi * 16 + g * 4 + r;
            u16* cp = cbase + (size_t)row * N + bn + wn + cidx;
#pragma unroll
            for (int ni = 0; ni < 4; ++ni)
                cp[ni * 16] = f2bf(acc[mi][ni][r]);
        }
    }
}

// ---------------- sum two bf16 partials -> f32 ----------------
__global__ __launch_bounds__(256) void sum2_f32_k(const u16* __restrict__ a,
                                                  const u16* __restrict__ b,
                                                  float* __restrict__ out, int n8) {
    int i = blockIdx.x * 256 + threadIdx.x;
    if (i >= n8) return;
    u16x8 va = reinterpret_cast<const u16x8*>(a)[i];
    u16x8 vb = reinterpret_cast<const u16x8*>(b)[i];
    f32x4 lo, hi;
#pragma unroll
    for (int j = 0; j < 4; ++j) {
        lo[j] = bf2f(va[j]) + bf2f(vb[j]);
        hi[j] = bf2f(va[4 + j]) + bf2f(vb[4 + j]);
    }
    reinterpret_cast<f32x4*>(out)[i * 2] = lo;
    reinterpret_cast<f32x4*>(out)[i * 2 + 1] = hi;
}

// ---------------- fused post-GEMM1: RMSNorm+RoPE (blocks 0..20479) + V-frag ----------------
__global__ __launch_bounds__(256) void postgemm_k(const u16* __restrict__ p0,
                                                  const u16* __restrict__ p1,
                                                  const float* __restrict__ cosb,
                                                  const float* __restrict__ sinb,
                                                  const float* __restrict__ qw,
                                                  const float* __restrict__ kw,
                                                  u16* __restrict__ qn,
                                                  u16* __restrict__ kfrag,
                                                  u16* __restrict__ vfrag) {
    __shared__ float t[64][65];
    int b = blockIdx.x;
    if (b < 20480) {
        int idx = b * 4 + (threadIdx.x >> 6);
        int lane = threadIdx.x & 63;
        int s = idx / 40, hh = idx - s * 40;
        size_t off = (hh < 32) ? ((size_t)s * 3072 + hh * 64 + lane)
                               : ((size_t)s * 3072 + 2048 + (hh - 32) * 64 + lane);
        float val = bf2f(p0[off]) + bf2f(p1[off]);
        float ss = val * val;
#pragma unroll
        for (int mm = 32; mm; mm >>= 1) ss += __shfl_xor(ss, mm);
        float w = (hh < 32) ? qw[lane] : kw[lane];
        float xn = val * rsqrtf(ss * (1.f / 64.f) + 1e-6f) * w;
        float part = __shfl_xor(xn, 32);
        float rot = (lane < 32) ? -part : part;
        float o = xn * cosb[s * 64 + lane] + rot * sinb[s * 64 + lane];
        if (hh < 32) {
            qn[(size_t)s * 2048 + hh * 64 + lane] = f2bf(o * (0.125f * LOG2E));
        } else {
            int h8 = hh - 32;
            int k32 = s & 31;
            int p32 = ((k32 >> 2) & 1) * 16 + ((k32 >> 3) << 2) + (k32 & 3);
            int p = (s & ~31) + p32;
            kfrag[(((size_t)h8 * 128 + (p >> 4)) << 10) + (lane >> 3) * 128 + (p & 15) * 8 + (lane & 7)] = f2bf(o);
        }
        return;
    }
    int vb = b - 20480;
    int s0 = (vb & 31) * 64, h = vb >> 5;
    int tx = threadIdx.x & 63, ty = threadIdx.x >> 6;
#pragma unroll
    for (int i = 0; i < 16; ++i) {
        int r = ty + i * 4;
        size_t off = (size_t)(s0 + r) * 3072 + 2560 + h * 64 + tx;
        t[r][tx] = bf2f(p0[off]) + bf2f(p1[off]);
    }
    __syncthreads();
    int dt = threadIdx.x >> 6, g = (threadIdx.x >> 4) & 3, cc = threadIdx.x & 15;
#pragma unroll
    for (int kb = 0; kb < 2; ++kb) {
        u16x8 o;
#pragma unroll
        for (int i = 0; i < 8; ++i) o[i] = f2bf(t[kb * 32 + g * 8 + i][dt * 16 + cc]);
        *reinterpret_cast<u16x8*>(
            &vfrag[((size_t)h * 64 + (s0 >> 5) + kb) * 2048 + dt * 512 + (size_t)(threadIdx.x & 63) * 8]) = o;
    }
}

// ---------------- Flash attention: 32 q-rows/wave, register-lifetime-ordered phases ----------------
// (R16 structure: loadK -> QK_A -> softmaxA -> QK_B -> softmaxB -> loadV -> PV both;
// K dead before V arrives -> peak regs fit the (64,4) cap for 4 waves/SIMD)
__global__ __launch_bounds__(64, 4) void attn_k(const u16* __restrict__ qn,
                                                const u16* __restrict__ kfrag,
                                                const u16* __restrict__ vfrag,
                                                u16* __restrict__ obuf,
                                                float* __restrict__ lbuf) {
    int h = blockIdx.x;
    int kvh = h >> 2;
    int lane = threadIdx.x;
    int item = 159 - blockIdx.y;
    int t, w;
    if (item < 16)      { t = item;                    w = 0; }
    else if (item < 48) { t = 16 + ((item - 16) >> 1); w = (item - 16) & 1; }
    else if (item < 96) { int r = item - 48; int q = r / 3; t = 32 + q; w = r - 3 * q; }
    else                { t = 48 + ((item - 96) >> 2); w = (item - 96) & 3; }

    int qA0 = t * 32;
    int qB0 = qA0 + 16;
    int kv0 = w * 512;
    int nkA = qA0 + 16, nkB = qB0 + 16;
    int kvend = (kv0 + 512 < nkB) ? (kv0 + 512) : nkB;

    int g = lane >> 4, cc = lane & 15;
    int qrowA = qA0 + cc, qrowB = qB0 + cc;

    const size_t qoffA = (size_t)qrowA * 2048 + h * 64;
    const size_t qoffB = (size_t)qrowB * 2048 + h * 64;
    bf16x8 qa0 = *reinterpret_cast<const bf16x8*>(&qn[qoffA + g * 8]);
    bf16x8 qa1 = *reinterpret_cast<const bf16x8*>(&qn[qoffA + 32 + g * 8]);
    bf16x8 qb0 = *reinterpret_cast<const bf16x8*>(&qn[qoffB + g * 8]);
    bf16x8 qb1 = *reinterpret_cast<const bf16x8*>(&qn[qoffB + 32 + g * 8]);

    float lA = 0.f, lB = 0.f;
    f32x4 oA[4] = {}, oB[4] = {};

    const u16* kbase = kfrag + (((size_t)kvh * 128) << 10) + lane * 8;
    const u16* vbase = vfrag + (size_t)kvh * 64 * 2048 + lane * 8;

#pragma unroll 1
    for (; kv0 < kvend; kv0 += 64) {
        bool doA = kv0 < nkA;
        u16x8 pbA[2], pbB[2];

        {
            bf16x8 kf0[4], kf1[4];
#pragma unroll
            for (int sub = 0; sub < 4; ++sub) {
                const u16* kp = kbase + (size_t)((kv0 >> 4) + sub) * 1024;
                kf0[sub] = *reinterpret_cast<const bf16x8*>(kp);
                kf1[sub] = *reinterpret_cast<const bf16x8*>(kp + 512);
            }
            if (doA) {
                f32x4 st[4];
                __builtin_amdgcn_s_setprio(1);
#pragma unroll
                for (int sub = 0; sub < 4; ++sub) {
                    st[sub] = __builtin_amdgcn_mfma_f32_16x16x32_bf16(kf0[sub], qa0, (f32x4){0.f, 0.f, 0.f, 0.f}, 0, 0, 0);
                    st[sub] = __builtin_amdgcn_mfma_f32_16x16x32_bf16(kf1[sub], qa1, st[sub], 0, 0, 0);
                }
                __builtin_amdgcn_s_setprio(0);
                if (kv0 + 64 > qA0) {
#pragma unroll
                    for (int sub = 0; sub < 4; ++sub)
#pragma unroll
                        for (int r = 0; r < 4; ++r) {
                            int key = kv0 + (sub >> 1) * 32 + g * 8 + (sub & 1) * 4 + r;
                            if (key > qrowA) st[sub][r] = -1e30f;
                        }
                }
                float rs = 0.f;
#pragma unroll
                for (int sub = 0; sub < 4; ++sub)
#pragma unroll
                    for (int r = 0; r < 4; ++r) {
                        float e = __builtin_amdgcn_exp2f(st[sub][r]);
                        rs += e;
                        pbA[sub >> 1][(sub & 1) * 4 + r] = f2bf(e);
                    }
                lA += rs;
            }
            f32x4 st[4];
            __builtin_amdgcn_s_setprio(1);
#pragma unroll
            for (int sub = 0; sub < 4; ++sub) {
                st[sub] = __builtin_amdgcn_mfma_f32_16x16x32_bf16(kf0[sub], qb0, (f32x4){0.f, 0.f, 0.f, 0.f}, 0, 0, 0);
                st[sub] = __builtin_amdgcn_mfma_f32_16x16x32_bf16(kf1[sub], qb1, st[sub], 0, 0, 0);
            }
            __builtin_amdgcn_s_setprio(0);
            if (kv0 + 64 > qB0) {
#pragma unroll
                for (int sub = 0; sub < 4; ++sub)
#pragma unroll
                    for (int r = 0; r < 4; ++r) {
                        int key = kv0 + (sub >> 1) * 32 + g * 8 + (sub & 1) * 4 + r;
                        if (key > qrowB) st[sub][r] = -1e30f;
                    }
            }
            float rs = 0.f;
#pragma unroll
            for (int sub = 0; sub < 4; ++sub)
#pragma unroll
                for (int r = 0; r < 4; ++r) {
                    float e = __builtin_amdgcn_exp2f(st[sub][r]);
                    rs += e;
                    pbB[sub >> 1][(sub & 1) * 4 + r] = f2bf(e);
                }
            lB += rs;
        }

        bf16x8 vv[2][4];
#pragma unroll
        for (int sp = 0; sp < 2; ++sp)
#pragma unroll
            for (int dt = 0; dt < 4; ++dt)
                vv[sp][dt] = *reinterpret_cast<const bf16x8*>(
                    vbase + (size_t)((kv0 >> 5) + sp) * 2048 + dt * 512);

        __builtin_amdgcn_s_setprio(1);
#pragma unroll
        for (int sp = 0; sp < 2; ++sp) {
            bf16x8 pa = __builtin_bit_cast(bf16x8, pbA[sp]);
            bf16x8 pb = __builtin_bit_cast(bf16x8, pbB[sp]);
#pragma unroll
            for (int dt = 0; dt < 4; ++dt) {
                if (doA) oA[dt] = __builtin_amdgcn_mfma_f32_16x16x32_bf16(vv[sp][dt], pa, oA[dt], 0, 0, 0);
                oB[dt] = __builtin_amdgcn_mfma_f32_16x16x32_bf16(vv[sp][dt], pb, oB[dt], 0, 0, 0);
            }
        }
        __builtin_amdgcn_s_setprio(0);
    }

    lA += __shfl_xor(lA, 16);
    lA += __shfl_xor(lA, 32);
    lB += __shfl_xor(lB, 16);
    lB += __shfl_xor(lB, 32);
    size_t slotA = ((size_t)h * 160 + item) * 2;
    if (lane < 16) {
        lbuf[slotA * 16 + cc] = lA;
        lbuf[(slotA + 1) * 16 + cc] = lB;
    }
    u16* spA = obuf + slotA * 1024;
    u16* spB = obuf + (slotA + 1) * 1024;
#pragma unroll
    for (int dt = 0; dt < 4; ++dt) {
        u16x4 ovA, ovB;
#pragma unroll
        for (int r = 0; r < 4; ++r) {
            ovA[r] = f2bf(oA[dt][r]);
            ovB[r] = f2bf(oB[dt][r]);
        }
        *reinterpret_cast<u16x4*>(&spA[cc * 64 + dt * 16 + g * 4]) = ovA;
        *reinterpret_cast<u16x4*>(&spB[cc * 64 + dt * 16 + g * 4]) = ovB;
    }
}

// ---------------- merge: attn_bf16 = sum(o_w) / (sum(l_w) + 2^(sink*log2e)) ----------------
__global__ __launch_bounds__(256) void merge_k(const u16* __restrict__ obuf,
                                               const float* __restrict__ lbuf,
                                               const float* __restrict__ sink,
                                               u16* __restrict__ attnb) {
    int row = blockIdx.x;
    int c = row >> 4, cc = row & 15;
    int t2 = c >> 1, half = c & 1;
    int nw = (t2 >> 4) + 1;
    int jb = (t2 < 16) ? t2
           : (t2 < 32) ? 16 + ((t2 - 16) << 1)
           : (t2 < 48) ? 48 + 3 * (t2 - 32)
                       : 96 + ((t2 - 48) << 2);
    int t = threadIdx.x;
    int h = t >> 3, col0 = (t & 7) * 8;

    float acc[8] = {};
    float lsum = __builtin_amdgcn_exp2f(sink[h] * LOG2E);
#pragma unroll 1
    for (int w = 0; w < nw; ++w) {
        size_t slot = ((size_t)h * 160 + jb + w) * 2 + half;
        lsum += lbuf[slot * 16 + cc];
        u16x8 v = *reinterpret_cast<const u16x8*>(&obuf[slot * 1024 + cc * 64 + col0]);
#pragma unroll
        for (int i = 0; i < 8; ++i) acc[i] += bf2f(v[i]);
    }
    float inv = 1.f / lsum;
    u16x8 ob;
#pragma unroll
    for (int i = 0; i < 8; ++i) ob[i] = f2bf(acc[i] * inv);
    *reinterpret_cast<u16x8*>(&attnb[(size_t)row * 2048 + h * 64 + col0]) = ob;
}

extern "C" void kernel_launch(void* const* d_in, const int* in_sizes, int n_in,
                              void* d_out, int out_size, void* d_ws, size_t ws_size,
                              hipStream_t stream) {
    const float* x    = (const float*)d_in[0];
    const float* cosb = (const float*)d_in[2];
    const float* sinb = (const float*)d_in[3];
    const float* wq   = (const float*)d_in[4];
    const float* wk   = (const float*)d_in[5];
    const float* wv   = (const float*)d_in[6];
    const float* wo   = (const float*)d_in[7];
    const float* qw   = (const float*)d_in[8];
    const float* kw   = (const float*)d_in[9];
    const float* sink = (const float*)d_in[10];
    float* out = (float*)d_out;

    char* ws = (char*)d_ws;
    size_t off = 0;
    auto alloc = [&](size_t bytes) {
        char* p = ws + off;
        off += (bytes + 255) & ~(size_t)255;
        return p;
    };
    u16*   xb    = (u16*)alloc((size_t)2048 * 2048 * 2);
    u16*   wqkvt = (u16*)alloc((size_t)3072 * 2048 * 2);
    u16*   wot   = (u16*)alloc((size_t)2048 * 2048 * 2);
    u16*   p0    = (u16*)alloc((size_t)2048 * 3072 * 2);
    u16*   p1    = (u16*)alloc((size_t)2048 * 3072 * 2);
    u16*   qnb   = (u16*)alloc((size_t)2048 * 2048 * 2);
    u16*   kfrag = (u16*)alloc((size_t)8 * 128 * 1024 * 2);
    u16*   vfrag = (u16*)alloc((size_t)8 * 64 * 2048 * 2);
    float* lbuf  = (float*)alloc((size_t)32 * 320 * 16 * 4);
    u16*   attnb = xb;
    u16*   obuf  = p0;
    u16*   o2p   = p0;

    prep_k<<<4608, 256, 0, stream>>>(x, wq, wk, wv, wo, xb, wqkvt, wot);

    gemm_bt_dbuf_k<<<dim3(24, 16, 2), 512, 0, stream>>>(xb, wqkvt, p0, 2048, 3072, 2048);
    postgemm_k<<<20736, 256, 0, stream>>>(p0, p1, cosb, sinb, qw, kw, qnb, kfrag, vfrag);

    attn_k<<<dim3(32, 160), 64, 0, stream>>>(qnb, kfrag, vfrag, obuf, lbuf);
    merge_k<<<2048, 256, 0, stream>>>(obuf, lbuf, sink, attnb);

    gemm_bt_dbuf_k<<<dim3(16, 16, 2), 512, 0, stream>>>(attnb, wot, o2p, 2048, 2048, 2048);
    sum2_f32_k<<<2048, 256, 0, stream>>>(o2p, o2p + (size_t)2048 * 2048, out, 2048 * 2048 / 8);
}